// Round 12
// baseline (131.756 us; speedup 1.0000x reference)
//
#include <hip/hip_runtime.h>

// LSTM B=4096, T=512, I=1, H=32 — MFMA, round 12: barrier-free bpermute island.
//
// Insight: wall = 512 steps x per-step CHAIN latency (all blocks parallel;
// TLP hides issue, never the recurrence chain). r11's 616cy chain = ~210
// issue + ~400 LDS exchange (ds_write -> lgkm drain -> s_barrier -> ds_read).
// This round removes LDS + barrier entirely:
//
// Island wave = 4 batches, 2 cells/lane (64 lanes x 2 = 4x32, zero waste).
// Lane (col,g): batch g, cells (col, col+16). All 8 gate tiles computed by
// the wave itself (8 independent MFMAs, fp16 single-pass). Exchange is
// IN-WAVE: pack (h_col, h_col16) as fp16 pair in one u32; under the k-perm
// (cell c <-> k = 2*(c&15)+(c>>4)), source lane (4g+j + 16b)'s u32 IS
// A-fragment word j (k-pair 8g+2j, 8g+2j+1) of batch b. So the exchange is
// exactly 4x ds_bpermute_b32 with precomputed indices: no repack, no
// barrier, no LDS, no bank conflicts.
//
// D-mapping (verified r6-r11): lane (col,g) reg0 of tile t = gate row
// (16t+col) of batch g (batch g's h at A-row 4g; A-rows !=0 mod 4 feed
// D-rows never read, so arbitrary content is harmless -> bpermute formula
// needs no masking). Tiles: t=0,1 -> i(cells 0-15 / 16-31), 2,3 -> f,
// 4,5 -> G(tanh), 6,7 -> o. Gate input scales folded into W_hh/W_ih/bias.
// h carried fp16 (RNE); per-step gate error ~6e-5 -> ~1e-3 total.

typedef float f32x4 __attribute__((ext_vector_type(4)));
typedef _Float16 f16x8 __attribute__((ext_vector_type(8)));

#define L2E 1.44269504088896340736f
#define MFMA16(a, b, c) __builtin_amdgcn_mfma_f32_16x16x32_f16((a), (b), (c), 0, 0, 0)

union H2U { _Float16 h; unsigned short u; };
union FRAG { int i[4]; f16x8 h; };

__device__ __forceinline__ float sig_pre(float t) {   // t = -L2E*g
    return __builtin_amdgcn_rcpf(1.0f + __builtin_amdgcn_exp2f(t));
}
__device__ __forceinline__ float tanh_pre(float t) {  // t = -2*L2E*g
    return fmaf(__builtin_amdgcn_rcpf(1.0f + __builtin_amdgcn_exp2f(t)), 2.0f, -1.0f);
}

__global__ __launch_bounds__(256, 1) void lstm_mfma_kernel(
    const float* __restrict__ x,      // [B, 512]
    const float* __restrict__ W_ih,   // [128]
    const float* __restrict__ W_hh,   // [128, 32]
    const float* __restrict__ b_ih,   // [128]
    const float* __restrict__ b_hh,   // [128]
    const float* __restrict__ W_lin,  // [32]
    const float* __restrict__ b_lin,  // [1]
    float* __restrict__ out,          // [B]
    int B)
{
    const int tid  = (int)threadIdx.x;
    const int wid  = tid >> 6;            // 4 independent island waves per block
    const int lane = tid & 63;
    const int col  = lane & 15;           // tile col = A-row = this lane's low cell
    const int g    = lane >> 4;           // batch slot & k-group

    // bpermute byte-indices: A-frag word j <- lane (4g+j + 16*(col>>2)).
    // (cols with col%4 != 0 fetch don't-care rows -> dead D-rows; harmless.)
    int bidx[4];
#pragma unroll
    for (int j = 0; j < 4; ++j) bidx[j] = ((4 * g + j) + 16 * (col >> 2)) << 2;

    // B-fragments for all 8 tiles, fp16, scales folded.
    // element 2j   = W[gr][4g+j]    (k even -> cell 4g+j)
    // element 2j+1 = W[gr][16+4g+j] (k odd  -> cell 16+4g+j)
    f16x8 bf[8];
    float wihs[8];
    f32x4 biasC[8];
#pragma unroll
    for (int t = 0; t < 8; ++t) {
        const int gr = t * 16 + col;
        const float sc = (t == 4 || t == 5) ? (-2.0f * L2E) : (-L2E);
        const float* wr = &W_hh[gr * 32];
        f16x8 bb;
#pragma unroll
        for (int j = 0; j < 4; ++j) {
            bb[2 * j + 0] = (_Float16)(wr[4 * g + j] * sc);
            bb[2 * j + 1] = (_Float16)(wr[16 + 4 * g + j] * sc);
        }
        bf[t] = bb;
        wihs[t] = W_ih[gr] * sc;
        const float bbias = (b_ih[gr] + b_hh[gr]) * sc;
        biasC[t] = f32x4{bbias, 0.0f, 0.0f, 0.0f};     // bias only in reg0
    }

    const int b_glob = blockIdx.x * 16 + wid * 4 + g;
    const int bc     = b_glob < B ? b_glob : (B - 1);
    const float* xb  = x + (size_t)bc * 512;

    float4 xA = *reinterpret_cast<const float4*>(xb);
    float4 xB = *reinterpret_cast<const float4*>(xb + 4);

    float cc0 = 0.0f, cc1 = 0.0f, h0 = 0.0f, h1 = 0.0f;

    for (int tc = 0; tc < 64; ++tc) {
        const int nbase = ((tc + 1) & 63) * 8;
        const float4 nA = *reinterpret_cast<const float4*>(xb + nbase);
        const float4 nB = *reinterpret_cast<const float4*>(xb + nbase + 4);
        const float xts[8] = {xA.x, xA.y, xA.z, xA.w, xB.x, xB.y, xB.z, xB.w};

#pragma unroll
        for (int s = 0; s < 8; ++s) {
            const float xt = xts[s];

            // pack this lane's two cells as fp16 pair (RNE), bpermute x4 = A-frag
            H2U p0, p1; p0.h = (_Float16)h0; p1.h = (_Float16)h1;
            const int hu = (int)((unsigned)p0.u | ((unsigned)p1.u << 16));

            FRAG fr;
#pragma unroll
            for (int j = 0; j < 4; ++j)
                fr.i[j] = __builtin_amdgcn_ds_bpermute(bidx[j], hu);

            // 8 independent MFMAs; lane (col,g) reg0 = gate (16t+col), batch g
            f32x4 acc[8];
#pragma unroll
            for (int t = 0; t < 8; ++t) acc[t] = MFMA16(fr.h, bf[t], biasC[t]);

            float gt[8];
#pragma unroll
            for (int t = 0; t < 8; ++t) gt[t] = fmaf(xt, wihs[t], acc[t][0]);

            // cell col (even tiles) and cell col+16 (odd tiles), independent chains
            const float i0 = sig_pre(gt[0]),  i1 = sig_pre(gt[1]);
            const float f0 = sig_pre(gt[2]),  f1 = sig_pre(gt[3]);
            const float G0 = tanh_pre(gt[4]), G1 = tanh_pre(gt[5]);
            const float o0 = sig_pre(gt[6]),  o1 = sig_pre(gt[7]);

            cc0 = fmaf(f0, cc0, i0 * G0);
            cc1 = fmaf(f1, cc1, i1 * G1);
            h0 = o0 * tanh_pre(cc0 * (-2.0f * L2E));
            h1 = o1 * tanh_pre(cc1 * (-2.0f * L2E));
        }
        xA = nA; xB = nB;
    }

    // out[b] = sum_cells h*W_lin + b_lin: reduce over the 16-lane batch group
    float part = h0 * W_lin[col] + h1 * W_lin[col + 16];
    part += __shfl_xor(part, 1, 64);
    part += __shfl_xor(part, 2, 64);
    part += __shfl_xor(part, 4, 64);
    part += __shfl_xor(part, 8, 64);
    if (col == 0 && b_glob < B) out[b_glob] = part + b_lin[0];
}

extern "C" void kernel_launch(void* const* d_in, const int* in_sizes, int n_in,
                              void* d_out, int out_size, void* d_ws, size_t ws_size,
                              hipStream_t stream) {
    const float* x     = (const float*)d_in[0];
    const float* W_ih  = (const float*)d_in[1];
    const float* W_hh  = (const float*)d_in[2];
    const float* b_ih  = (const float*)d_in[3];
    const float* b_hh  = (const float*)d_in[4];
    const float* W_lin = (const float*)d_in[5];
    const float* b_lin = (const float*)d_in[6];
    float* out = (float*)d_out;

    const int B = in_sizes[0] / 512;          // x is [B, 512, 1]
    const int blocks = (B + 15) / 16;         // 16 batches per 256-thread block

    lstm_mfma_kernel<<<blocks, 256, 0, stream>>>(x, W_ih, W_hh, b_ih, b_hh,
                                                 W_lin, b_lin, out, B);
}